// Round 1
// baseline (5482.561 us; speedup 1.0000x reference)
//
#include <hip/hip_runtime.h>
#include <math.h>

#define NB 256
#define NH 512
#define NIN 512
#define NT 128
#define NG 2048   // 4*H gate rows

// Persistent state in module data segment — capture-safe, ws-independent.
__device__ float g_h0[NB * NH];
__device__ float g_h1[NB * NH];
__device__ float g_c [NB * NH];
// Hoisted input projection xg[t][b][g] = chain_k x[t][b][k]*w_ih[g][k]  (256 MB)
__device__ float g_xg[(size_t)NT * NB * NG];

// ---------------------------------------------------------------------------
__global__ __launch_bounds__(256) void zero_state() {
    int i = blockIdx.x * 256 + threadIdx.x;   // grid 512*256 = NB*NH
    g_h0[i] = 0.f;
    g_c[i]  = 0.f;
}

// ---------------------------------------------------------------------------
// xg = x @ w_ih^T  : M=NT*NB=32768, N=NG=2048, K=512.
// Strict ascending-k fp32 fma chain per output (sgemm microkernel semantics),
// identical to the per-step phase-0 chains of the previous kernel.
// BM=BN=128, BK=16, 256 threads, 8x8 microtile, LDS double-buffered with
// register prefetch (1 barrier per K-tile).
#define BM 128
#define BN 128
#define BK 16

__global__ __launch_bounds__(256, 2) void xg_gemm(
    const float* __restrict__ x,      // [M][512]
    const float* __restrict__ w_ih)   // [2048][512]
{
    __shared__ float As[2][BK][BM + 4];   // k-major, +4 pad (stride%32 = 4)
    __shared__ float Bs[2][BK][BN + 4];

    const int tid = threadIdx.x;
    const int bm = blockIdx.x >> 4;       // 256 m-blocks
    const int bn = blockIdx.x & 15;       // 16 n-blocks
    const size_t m0 = (size_t)bm * BM;
    const int n0 = bn * BN;

    // staging: row = tid>>1 (0..127), k-float base = (tid&1)*8; 16 floats/row
    const int srow = tid >> 1;
    const int sc4  = (tid & 1) * 8;
    const float* __restrict__ Arow = x    + (m0 + srow) * NIN;
    const float* __restrict__ Brow = w_ih + (size_t)(n0 + srow) * NIN;

    // microkernel: tx=n-group (16-way, 2-way bank = free), ty=m-group (broadcast)
    const int tx = tid & 15;
    const int ty = tid >> 4;

    float acc[8][8];
    #pragma unroll
    for (int i = 0; i < 8; ++i)
        #pragma unroll
        for (int j = 0; j < 8; ++j) acc[i][j] = 0.f;

    float4 ar0, ar1, br0, br1;

#define LOAD_TILE(kb) do {                                   \
        ar0 = *(const float4*)(Arow + (kb) + sc4);           \
        ar1 = *(const float4*)(Arow + (kb) + sc4 + 4);       \
        br0 = *(const float4*)(Brow + (kb) + sc4);           \
        br1 = *(const float4*)(Brow + (kb) + sc4 + 4);       \
    } while (0)

#define STORE_TILE(buf) do {                                             \
        As[buf][sc4+0][srow] = ar0.x; As[buf][sc4+1][srow] = ar0.y;      \
        As[buf][sc4+2][srow] = ar0.z; As[buf][sc4+3][srow] = ar0.w;      \
        As[buf][sc4+4][srow] = ar1.x; As[buf][sc4+5][srow] = ar1.y;      \
        As[buf][sc4+6][srow] = ar1.z; As[buf][sc4+7][srow] = ar1.w;      \
        Bs[buf][sc4+0][srow] = br0.x; Bs[buf][sc4+1][srow] = br0.y;      \
        Bs[buf][sc4+2][srow] = br0.z; Bs[buf][sc4+3][srow] = br0.w;      \
        Bs[buf][sc4+4][srow] = br1.x; Bs[buf][sc4+5][srow] = br1.y;      \
        Bs[buf][sc4+6][srow] = br1.z; Bs[buf][sc4+7][srow] = br1.w;      \
    } while (0)

    auto mk = [&](int buf) {
        #pragma unroll
        for (int k = 0; k < BK; ++k) {
            const float4 a0 = *(const float4*)(&As[buf][k][ty * 4]);
            const float4 a1 = *(const float4*)(&As[buf][k][64 + ty * 4]);
            const float4 b0 = *(const float4*)(&Bs[buf][k][tx * 4]);
            const float4 b1 = *(const float4*)(&Bs[buf][k][64 + tx * 4]);
            const float av[8] = {a0.x, a0.y, a0.z, a0.w, a1.x, a1.y, a1.z, a1.w};
            const float bv[8] = {b0.x, b0.y, b0.z, b0.w, b1.x, b1.y, b1.z, b1.w};
            #pragma unroll
            for (int i = 0; i < 8; ++i)
                #pragma unroll
                for (int j = 0; j < 8; ++j)
                    acc[i][j] = fmaf(av[i], bv[j], acc[i][j]);  // one fma per k, ascending
        }
    };

    LOAD_TILE(0);
    STORE_TILE(0);
    __syncthreads();
    for (int tt = 0; tt < 31; ++tt) {
        LOAD_TILE((tt + 1) * BK);     // prefetch next tile to regs (latency hidden by mk)
        mk(tt & 1);
        STORE_TILE((tt + 1) & 1);     // other buffer: safe with single barrier
        __syncthreads();
    }
    mk(1);                            // tile 31

    #pragma unroll
    for (int i = 0; i < 8; ++i) {
        const int mr = (i < 4) ? (ty * 4 + i) : (64 + ty * 4 + i - 4);
        float* __restrict__ orow = g_xg + (m0 + mr) * NG + n0;
        *(float4*)(orow + tx * 4)      = make_float4(acc[i][0], acc[i][1], acc[i][2], acc[i][3]);
        *(float4*)(orow + 64 + tx * 4) = make_float4(acc[i][4], acc[i][5], acc[i][6], acc[i][7]);
    }
#undef LOAD_TILE
#undef STORE_TILE
}

// ---------------------------------------------------------------------------
// Recurrent step: gates = xg_t + h @ w_hh^T (+biases), spike, c/h update.
// Block = 32 batch rows x 16 j cols (x4 gates). Thread = 2b x 1j x 4q = 8
// strict ascending-k chains. 64-k LDS chunks, double-buffered, reg prefetch.
#define SB 32
#define SJ 16
#define SK 64

__global__ __launch_bounds__(256) void step2(
    const float* __restrict__ w_hh,   // [2048][512]
    const float* __restrict__ b_ih,   // [2048]
    const float* __restrict__ b_hh,   // [2048]
    int t, int dir)
{
    const float* __restrict__ h_in  = dir ? g_h1 : g_h0;
    float* __restrict__       h_out = dir ? g_h0 : g_h1;

    __shared__ float Wl[2][64][SK + 4];   // 64 gate rows (q*16+jl), stride%32=4
    __shared__ float Hl[2][SB][SK + 4];

    const int tid = threadIdx.x;
    const int jb = blockIdx.x & 31;       // 32 j-chunks
    const int bb = blockIdx.x >> 5;       // 8 b-chunks
    const int j0 = jb * SJ;
    const int b0 = bb * SB;

    // staging maps (same proven pattern as previous kernel)
    const int wr = tid >> 2;              // w row 0..63
    const int wf = tid & 3;               // float4 col base
    const int wq = wr >> 4, wjl = wr & 15;
    const float* __restrict__ Wrow = w_hh + (size_t)(wq * NH + j0 + wjl) * NH;
    const int hr = tid >> 3;              // h row 0..31
    const int hc = tid & 7;
    const float* __restrict__ Hrow = h_in + (size_t)(b0 + hr) * NH;

    // microkernel map: jj in 0..15 (2-way LDS bank = free), bg in 0..15
    const int jj = tid & 15;
    const int bg = tid >> 4;

    float acc[2][4];                      // [b-sub][gate] strict f32 chains
    #pragma unroll
    for (int ib = 0; ib < 2; ++ib)
        #pragma unroll
        for (int q = 0; q < 4; ++q) acc[ib][q] = 0.f;

    float4 wreg[4], hreg[2];

    auto load_chunk = [&](int kb) {
        #pragma unroll
        for (int i = 0; i < 4; ++i)
            wreg[i] = *(const float4*)(Wrow + kb + (wf + 4 * i) * 4);
        #pragma unroll
        for (int i = 0; i < 2; ++i)
            hreg[i] = *(const float4*)(Hrow + kb + (hc + 8 * i) * 4);
    };
    auto store_chunk = [&](int buf) {
        #pragma unroll
        for (int i = 0; i < 4; ++i)
            *(float4*)(&Wl[buf][wr][(wf + 4 * i) * 4]) = wreg[i];
        #pragma unroll
        for (int i = 0; i < 2; ++i)
            *(float4*)(&Hl[buf][hr][(hc + 8 * i) * 4]) = hreg[i];
    };
    auto mk = [&](int buf) {
        #pragma unroll
        for (int kk = 0; kk < SK; kk += 4) {
            const float4 h0 = *(const float4*)(&Hl[buf][bg * 2 + 0][kk]);
            const float4 h1 = *(const float4*)(&Hl[buf][bg * 2 + 1][kk]);
            #pragma unroll
            for (int q = 0; q < 4; ++q) {
                const float4 w4 = *(const float4*)(&Wl[buf][q * 16 + jj][kk]);
                float a0 = acc[0][q], a1 = acc[1][q];
                a0 = fmaf(h0.x, w4.x, a0); a1 = fmaf(h1.x, w4.x, a1);
                a0 = fmaf(h0.y, w4.y, a0); a1 = fmaf(h1.y, w4.y, a1);
                a0 = fmaf(h0.z, w4.z, a0); a1 = fmaf(h1.z, w4.z, a1);
                a0 = fmaf(h0.w, w4.w, a0); a1 = fmaf(h1.w, w4.w, a1);
                acc[0][q] = a0; acc[1][q] = a1;
            }
        }
    };

    load_chunk(0);
    store_chunk(0);
    __syncthreads();
    for (int tc = 0; tc < 7; ++tc) {
        load_chunk((tc + 1) * SK);
        mk(tc & 1);
        store_chunk((tc + 1) & 1);
        __syncthreads();
    }
    mk(1);                                // chunk 7

    // gates: ((xg + b_ih) + hW) + b_hh — reference grouping, all fp32
    #pragma unroll
    for (int ib = 0; ib < 2; ++ib) {
        const int b = b0 + bg * 2 + ib;
        const int j = j0 + jj;
        const float* __restrict__ xr = g_xg + ((size_t)t * NB + b) * NG;
        float s[4];
        #pragma unroll
        for (int q = 0; q < 4; ++q) {
            const int g = q * NH + j;
            const float gate = ((xr[g] + b_ih[g]) + acc[ib][q]) + b_hh[g];
            s[q] = (gate >= 0.0f) ? 1.f : 0.f;
        }
        const size_t idx = (size_t)b * NH + j;
        const float cv = g_c[idx];
        const float cn = s[1] * cv + s[0] * s[2];   // c = f*c + i*g (exact int)
        g_c[idx] = cn;
        h_out[idx] = cn * s[3];                     // h = c*o (exact int)
    }
}

// ---------------------------------------------------------------------------
// logits = g_h0 @ fc_w^T + fc_b (strict f32 fma chains); stable f32 softmax.
// One block per batch row: 64 threads stage h row in LDS, 10 threads chain.
__global__ __launch_bounds__(64) void final2(
    const float* __restrict__ fc_w,
    const float* __restrict__ fc_b,
    float* __restrict__ out)
{
    __shared__ float hl[NH];
    __shared__ float ls[10];
    const int b = blockIdx.x;
    const int tid = threadIdx.x;
    const float* __restrict__ hb = g_h0 + (size_t)b * NH;
    *(float4*)(&hl[tid * 4])       = *(const float4*)(hb + tid * 4);
    *(float4*)(&hl[256 + tid * 4]) = *(const float4*)(hb + 256 + tid * 4);
    __syncthreads();
    if (tid < 10) {
        float a = 0.f;
        const float* __restrict__ wr = fc_w + (size_t)tid * NH;
        for (int j = 0; j < NH; j += 4) {
            const float4 w4 = *(const float4*)(wr + j);
            a = fmaf(hl[j + 0], w4.x, a);
            a = fmaf(hl[j + 1], w4.y, a);
            a = fmaf(hl[j + 2], w4.z, a);
            a = fmaf(hl[j + 3], w4.w, a);
        }
        ls[tid] = a + fc_b[tid];
    }
    __syncthreads();
    if (tid == 0) {
        float m = -3.4e38f;
        #pragma unroll
        for (int o = 0; o < 10; ++o) m = (ls[o] > m) ? ls[o] : m;
        float e[10], ssum = 0.f;
        #pragma unroll
        for (int o = 0; o < 10; ++o) { e[o] = expf(ls[o] - m); ssum += e[o]; }
        const float inv = 1.0f / ssum;
        #pragma unroll
        for (int o = 0; o < 10; ++o) out[b * 10 + o] = e[o] * inv;
    }
}

// ---------------------------------------------------------------------------
extern "C" void kernel_launch(void* const* d_in, const int* in_sizes, int n_in,
                              void* d_out, int out_size, void* d_ws, size_t ws_size,
                              hipStream_t stream) {
    const float* x    = (const float*)d_in[0];
    const float* w_ih = (const float*)d_in[1];
    const float* b_ih = (const float*)d_in[2];
    const float* w_hh = (const float*)d_in[3];
    const float* b_hh = (const float*)d_in[4];
    const float* fc_w = (const float*)d_in[5];
    const float* fc_b = (const float*)d_in[6];
    float* out = (float*)d_out;

    zero_state<<<512, 256, 0, stream>>>();

    // Hoisted input projection: one parallel GEMM for all 128 timesteps.
    xg_gemm<<<4096, 256, 0, stream>>>(x, w_ih);

    // Sequential recurrence: only the h-dependent half remains per step.
    for (int t = 0; t < NT; ++t) {
        step2<<<256, 256, 0, stream>>>(w_hh, b_ih, b_hh, t, t & 1);
    }
    // NT=128 even: last step (t=127, dir=1) wrote g_h0.
    final2<<<256, 64, 0, stream>>>(fc_w, fc_b, out);
}